// Round 1
// baseline (752.158 us; speedup 1.0000x reference)
//
#include <hip/hip_runtime.h>
#include <hip/hip_bf16.h>
#include <math.h>

// ---------------------------------------------------------------------------
// RPN fused kernel for MI355X (gfx950)
//   trunk : 3x3 conv 64->512 + bias + relu   (bf16x2 split MFMA, 3 passes)
//   heads : 1x1 conv 512->9 (sigmoid) and 512->36 (linear), deltas masked by
//           score > 0.7, output [B,H,W,45] fp32
// ---------------------------------------------------------------------------

typedef __bf16 bf16x8 __attribute__((ext_vector_type(8)));
typedef __bf16 bf16x4 __attribute__((ext_vector_type(4)));
typedef float  f32x4  __attribute__((ext_vector_type(4)));

#define BT_ELEMS  (18 * 512 * 32)   // 294912  trunk weights, [s][n][kk] k-major
#define BT2_ELEMS (48 * 512)        // 24576   head weights,  [o][k]     k-major

// ---------------------------------------------------------------------------
// prep: split fp32 weights into bf16 hi/lo, transposed to k-major layouts
// ---------------------------------------------------------------------------
__global__ __launch_bounds__(256) void rpn_prep(
    const float* __restrict__ wb,   // [3][3][64][512]
    const float* __restrict__ wc,   // [512][9]
    const float* __restrict__ wr,   // [512][36]
    __bf16* __restrict__ bt_hi, __bf16* __restrict__ bt_lo,
    __bf16* __restrict__ bt2_hi, __bf16* __restrict__ bt2_lo)
{
    int t = blockIdx.x * 256 + threadIdx.x;
    if (t < BT_ELEMS) {
        int kk = t & 31;
        int n  = (t >> 5) & 511;
        int s  = t >> 14;                 // 0..17
        int kg = s * 32 + kk;             // 0..575
        int tap = kg >> 6, c = kg & 63;   // k = (ky*3+kx)*64 + c
        float v = wb[(tap * 64 + c) * 512 + n];
        __bf16 h = (__bf16)v;
        bt_hi[t] = h;
        bt_lo[t] = (__bf16)(v - (float)h);
    } else if (t < BT_ELEMS + BT2_ELEMS) {
        int j = t - BT_ELEMS;
        int k = j & 511;
        int o = j >> 9;                   // 0..47
        float v = 0.f;
        if (o < 9)       v = wc[k * 9 + o];
        else if (o < 45) v = wr[k * 36 + (o - 9)];
        __bf16 h = (__bf16)v;
        bt2_hi[j] = h;
        bt2_lo[j] = (__bf16)(v - (float)h);
    }
}

// ---------------------------------------------------------------------------
// main fused kernel: 4096 workgroups x 256 threads
//   tile = 64 output positions (2 h-rows x 32 w) x 512 channels
//   wave w owns channel slice [128w, 128w+128)
// LDS arena (48 KB), phase-overlapped:
//   phase1: xs_hi [4][34][72] bf16 @0 (19584 B), xs_lo @19584 (19584 B)
//   phase2: zbuf  float[64][48] @0 (12288 B),
//           fbuf per wave @12288 + w*9216: fh [64][36] bf16, fl +4608 B
// ---------------------------------------------------------------------------
#define XS_LO_OFF   19584
#define FB_OFF      12288
#define FB_PER_WAVE 9216
#define ARENA_BYTES 49152

__global__ __launch_bounds__(256, 2) void rpn_main(
    const float* __restrict__ x,        // [4][256][256][64]
    const float* __restrict__ b_base,   // [512]
    const float* __restrict__ b_cls,    // [9]
    const float* __restrict__ b_reg,    // [36]
    const __bf16* __restrict__ bt_hi, const __bf16* __restrict__ bt_lo,
    const __bf16* __restrict__ bt2_hi, const __bf16* __restrict__ bt2_lo,
    float* __restrict__ out)            // [4][256][256][45]
{
    __shared__ char smem[ARENA_BYTES];
    __bf16* xs_hi = (__bf16*)smem;
    __bf16* xs_lo = (__bf16*)(smem + XS_LO_OFF);
    float*  zbuf  = (float*)smem;

    const int tid  = threadIdx.x;
    const int wave = tid >> 6;
    const int lane = tid & 63;
    const int q    = lane >> 4;     // 0..3
    const int lr   = lane & 15;     // 0..15
    const int n0   = wave * 128;    // wave's channel-slice base

    const int wg  = blockIdx.x;
    const int b   = wg >> 10;           // 1024 tiles per image
    const int rem = wg & 1023;
    const int h0  = (rem >> 3) * 2;     // 2 h-rows per tile
    const int w0  = (rem & 7) * 32;     // 32 w-positions per tile

    // ---- stage x patch (4 rows x 34 pos x 64 ch) as bf16 hi/lo ----
    for (int i = 0; i < 9; ++i) {
        int flat = tid + i * 256;
        if (flat < 4 * 34 * 16) {
            int cq  = flat & 15;          // channel quad
            int rp  = flat >> 4;          // 0..135
            int row = rp / 34;
            int pos = rp - row * 34;
            int hh  = h0 - 1 + row;
            int ww  = w0 - 1 + pos;
            bf16x4 h4, l4;
            if (hh >= 0 && hh < 256 && ww >= 0 && ww < 256) {
                const float4 v = *(const float4*)&x[(((b * 256 + hh) * 256 + ww) * 64 + cq * 4)];
                float vs[4] = {v.x, v.y, v.z, v.w};
                #pragma unroll
                for (int j = 0; j < 4; ++j) {
                    __bf16 h = (__bf16)vs[j];
                    h4[j] = h;
                    l4[j] = (__bf16)(vs[j] - (float)h);
                }
            } else {
                #pragma unroll
                for (int j = 0; j < 4; ++j) { h4[j] = (__bf16)0.f; l4[j] = (__bf16)0.f; }
            }
            int off = (row * 34 + pos) * 72 + cq * 4;
            *(bf16x4*)&xs_hi[off] = h4;
            *(bf16x4*)&xs_lo[off] = l4;
        }
    }
    __syncthreads();   // barrier 1: xs ready

    // ---- trunk K-loop: 18 k-steps of 32, barrier-free ----
    f32x4 acc[4][8];
    #pragma unroll
    for (int km = 0; km < 4; ++km)
        #pragma unroll
        for (int l = 0; l < 8; ++l)
            acc[km][l] = (f32x4){0.f, 0.f, 0.f, 0.f};

    // prefetch b-frags for (s=0, l=0); loads are 1 KB/wave fully coalesced
    bf16x8 bhn, bln;
    {
        int eo = ((0 * 512 + n0 + lr) * 32 + q * 8);
        bhn = *(const bf16x8*)(bt_hi + eo);
        bln = *(const bf16x8*)(bt_lo + eo);
    }

    for (int s = 0; s < 18; ++s) {
        const int tap = s >> 1;
        const int ky  = tap / 3;
        const int kx  = tap - ky * 3;
        const int c0  = (s & 1) * 32 + q * 8;
        bf16x8 ah[4], al[4];
        #pragma unroll
        for (int km = 0; km < 4; ++km) {
            int rowp = (km >> 1) + ky;
            int pos  = ((km & 1) << 4) + lr + kx;
            int off  = (rowp * 34 + pos) * 72 + c0;
            ah[km] = *(const bf16x8*)&xs_hi[off];
            al[km] = *(const bf16x8*)&xs_lo[off];
        }
        #pragma unroll
        for (int l = 0; l < 8; ++l) {
            bf16x8 bh = bhn, bl = bln;
            int si = s * 8 + l + 1;
            if (si > 143) si = 143;          // harmless reload at the end
            int sn = si >> 3, ln = si & 7;
            int eo = ((sn * 512 + n0 + ln * 16 + lr) * 32 + q * 8);
            bhn = *(const bf16x8*)(bt_hi + eo);
            bln = *(const bf16x8*)(bt_lo + eo);
            #pragma unroll
            for (int km = 0; km < 4; ++km)
                acc[km][l] = __builtin_amdgcn_mfma_f32_16x16x32_bf16(ah[km], bh, acc[km][l], 0, 0, 0);
            #pragma unroll
            for (int km = 0; km < 4; ++km)
                acc[km][l] = __builtin_amdgcn_mfma_f32_16x16x32_bf16(ah[km], bl, acc[km][l], 0, 0, 0);
            #pragma unroll
            for (int km = 0; km < 4; ++km)
                acc[km][l] = __builtin_amdgcn_mfma_f32_16x16x32_bf16(al[km], bh, acc[km][l], 0, 0, 0);
        }
    }

    __syncthreads();   // barrier 2: xs dead, safe to reuse arena

    // zero the z accumulation buffer
    for (int i = tid; i < 64 * 48; i += 256) zbuf[i] = 0.f;
    __syncthreads();   // barrier 3: zbuf zeroed

    // ---- fused 1x1 heads: per-wave k-slice GEMM feat[64][128] x w2[128][48] ----
    __bf16* fh = (__bf16*)(smem + FB_OFF + wave * FB_PER_WAVE);
    __bf16* fl = fh + 64 * 36;

    f32x4 acc2[4][3];
    #pragma unroll
    for (int km = 0; km < 4; ++km)
        #pragma unroll
        for (int ns = 0; ns < 3; ++ns)
            acc2[km][ns] = (f32x4){0.f, 0.f, 0.f, 0.f};

    for (int sub = 0; sub < 4; ++sub) {       // 4 k-chunks of 32 within the slice
        // dump this wave's 32-channel slice of feat (bias+relu, bf16 hi/lo)
        #pragma unroll
        for (int lh = 0; lh < 2; ++lh) {
            int l = sub * 2 + lh;
            float bias = b_base[n0 + l * 16 + lr];
            #pragma unroll
            for (int km = 0; km < 4; ++km) {
                #pragma unroll
                for (int r = 0; r < 4; ++r) {
                    float v = acc[km][l][r] + bias;
                    v = v > 0.f ? v : 0.f;
                    __bf16 h = (__bf16)v;
                    int row = km * 16 + q * 4 + r;
                    int col = lh * 16 + lr;
                    fh[row * 36 + col] = h;
                    fl[row * 36 + col] = (__bf16)(v - (float)h);
                }
            }
        }
        asm volatile("s_waitcnt lgkmcnt(0)" ::: "memory");  // wave-local RAW fence

        // A-frags: feat rows, k-local = q*8..q*8+7 (8-byte aligned -> 2x b64)
        bf16x8 fah[4], fal[4];
        #pragma unroll
        for (int km = 0; km < 4; ++km) {
            int off = (km * 16 + lr) * 36 + q * 8;
            union { bf16x8 v8; bf16x4 v4[2]; } uh, ul;
            uh.v4[0] = *(const bf16x4*)&fh[off];
            uh.v4[1] = *(const bf16x4*)&fh[off + 4];
            ul.v4[0] = *(const bf16x4*)&fl[off];
            ul.v4[1] = *(const bf16x4*)&fl[off + 4];
            fah[km] = uh.v8;
            fal[km] = ul.v8;
        }

        const int kg = n0 + sub * 32 + q * 8;   // global k for B frags
        // ns = 0 (contains the 9 score cols): 3-pass hi/lo
        {
            int eo = (0 * 16 + lr) * 512 + kg;
            bf16x8 wh = *(const bf16x8*)&bt2_hi[eo];
            bf16x8 wl = *(const bf16x8*)&bt2_lo[eo];
            #pragma unroll
            for (int km = 0; km < 4; ++km)
                acc2[km][0] = __builtin_amdgcn_mfma_f32_16x16x32_bf16(fah[km], wh, acc2[km][0], 0, 0, 0);
            #pragma unroll
            for (int km = 0; km < 4; ++km)
                acc2[km][0] = __builtin_amdgcn_mfma_f32_16x16x32_bf16(fah[km], wl, acc2[km][0], 0, 0, 0);
            #pragma unroll
            for (int km = 0; km < 4; ++km)
                acc2[km][0] = __builtin_amdgcn_mfma_f32_16x16x32_bf16(fal[km], wh, acc2[km][0], 0, 0, 0);
        }
        // ns = 1,2 (pure delta cols): single pass
        #pragma unroll
        for (int ns = 1; ns < 3; ++ns) {
            int eo = (ns * 16 + lr) * 512 + kg;
            bf16x8 wh = *(const bf16x8*)&bt2_hi[eo];
            #pragma unroll
            for (int km = 0; km < 4; ++km)
                acc2[km][ns] = __builtin_amdgcn_mfma_f32_16x16x32_bf16(fah[km], wh, acc2[km][ns], 0, 0, 0);
        }
    }

    // k-slice reduction across waves
    #pragma unroll
    for (int km = 0; km < 4; ++km)
        #pragma unroll
        for (int ns = 0; ns < 3; ++ns)
            #pragma unroll
            for (int r = 0; r < 4; ++r) {
                int row = km * 16 + q * 4 + r;
                int col = ns * 16 + lr;
                atomicAdd(&zbuf[row * 48 + col], acc2[km][ns][r]);
            }
    __syncthreads();   // barrier 4: z complete

    // ---- epilogue: sigmoid, threshold mask, store ----
    for (int i = tid; i < 64 * 45; i += 256) {
        int m = i / 45;
        int o = i - m * 45;
        float z = zbuf[m * 48 + o];
        float v;
        if (o < 9) {
            v = 1.f / (1.f + expf(-(z + b_cls[o])));
        } else {
            int d = o - 9;
            int a = d >> 2;
            float s = 1.f / (1.f + expf(-(zbuf[m * 48 + a] + b_cls[a])));
            v = (s > 0.7f) ? (z + b_reg[d]) : 0.f;
        }
        int mh = m >> 5, mw = m & 31;
        out[(((b * 256 + h0 + mh) * 256) + w0 + mw) * 45 + o] = v;
    }
}

// ---------------------------------------------------------------------------
extern "C" void kernel_launch(void* const* d_in, const int* in_sizes, int n_in,
                              void* d_out, int out_size, void* d_ws, size_t ws_size,
                              hipStream_t stream)
{
    const float* x      = (const float*)d_in[0];
    const float* w_base = (const float*)d_in[1];
    const float* b_base = (const float*)d_in[2];
    const float* w_cls  = (const float*)d_in[3];
    const float* b_cls  = (const float*)d_in[4];
    const float* w_reg  = (const float*)d_in[5];
    const float* b_reg  = (const float*)d_in[6];
    float* out = (float*)d_out;

    __bf16* bt_hi  = (__bf16*)d_ws;
    __bf16* bt_lo  = bt_hi + BT_ELEMS;
    __bf16* bt2_hi = bt_lo + BT_ELEMS;
    __bf16* bt2_lo = bt2_hi + BT2_ELEMS;

    rpn_prep<<<(BT_ELEMS + BT2_ELEMS) / 256, 256, 0, stream>>>(
        w_base, w_cls, w_reg, bt_hi, bt_lo, bt2_hi, bt2_lo);
    rpn_main<<<4096, 256, 0, stream>>>(
        x, b_base, b_cls, b_reg, bt_hi, bt_lo, bt2_hi, bt2_lo, out);
}

// Round 2
// 680.229 us; speedup vs baseline: 1.1057x; 1.1057x over previous
//
#include <hip/hip_runtime.h>
#include <hip/hip_bf16.h>
#include <math.h>

// ---------------------------------------------------------------------------
// RPN fused kernel for MI355X (gfx950)
//   trunk : 3x3 conv 64->512 + bias + relu   (bf16x2 split MFMA, 3 passes)
//   heads : 1x1 conv 512->9 (sigmoid) and 512->36 (linear), deltas masked by
//           score > 0.7, output [B,H,W,45] fp32
// Round 2: trunk weights re-laid-out in lane-access order ([si][tid][hi8|lo8])
//          + depth-4 rotating register prefetch (8 loads in flight) to cover
//          L2 latency. Everything else unchanged from the passing round-1 run.
// ---------------------------------------------------------------------------

typedef __bf16 bf16x8 __attribute__((ext_vector_type(8)));
typedef __bf16 bf16x4 __attribute__((ext_vector_type(4)));
typedef float  f32x4  __attribute__((ext_vector_type(4)));

#define SI_STEPS  144                   // 18 k-chunks x 8 n-subtiles
#define SI_SLOTS  148                   // +4 pad slots for prefetch overrun
#define BTI_ELEMS (SI_SLOTS * 256 * 16) // interleaved trunk weights (bf16)
#define BT2_ELEMS (48 * 512)            // head weights, [o][k] k-major

// ---------------------------------------------------------------------------
// prep: split fp32 weights into bf16 hi/lo
//   trunk  -> btI[si][tid][hi8|lo8]  (exact per-lane load order of rpn_main)
//   heads  -> bt2_hi/bt2_lo [o][k]
// ---------------------------------------------------------------------------
__global__ __launch_bounds__(256) void rpn_prep(
    const float* __restrict__ wb,   // [3][3][64][512]
    const float* __restrict__ wc,   // [512][9]
    const float* __restrict__ wr,   // [512][36]
    __bf16* __restrict__ btI,
    __bf16* __restrict__ bt2_hi, __bf16* __restrict__ bt2_lo)
{
    int t = blockIdx.x * 256 + threadIdx.x;
    if (t < SI_STEPS * 256 * 8) {
        int j    = t & 7;
        int lane = (t >> 3) & 63;
        int wv   = (t >> 9) & 3;
        int si   = t >> 11;              // 0..143
        int s    = si >> 3;              // k-chunk 0..17
        int l    = si & 7;               // n-subtile 0..7
        int lr   = lane & 15;
        int q    = lane >> 4;
        int n    = wv * 128 + l * 16 + lr;
        int kg   = s * 32 + q * 8 + j;   // 0..575
        int tap  = kg >> 6, c = kg & 63; // k = (ky*3+kx)*64 + c
        float v  = wb[(tap * 64 + c) * 512 + n];
        __bf16 h = (__bf16)v;
        int base = (si * 256 + wv * 64 + lane) * 16;
        btI[base + j]     = h;
        btI[base + 8 + j] = (__bf16)(v - (float)h);
    } else if (t < SI_STEPS * 256 * 8 + BT2_ELEMS) {
        int jj = t - SI_STEPS * 256 * 8;
        int k = jj & 511;
        int o = jj >> 9;                 // 0..47
        float v = 0.f;
        if (o < 9)       v = wc[k * 9 + o];
        else if (o < 45) v = wr[k * 36 + (o - 9)];
        __bf16 h = (__bf16)v;
        bt2_hi[jj] = h;
        bt2_lo[jj] = (__bf16)(v - (float)h);
    }
}

// ---------------------------------------------------------------------------
// main fused kernel: 4096 workgroups x 256 threads
//   tile = 64 output positions (2 h-rows x 32 w) x 512 channels
//   wave w owns channel slice [128w, 128w+128)
// LDS arena (48 KB), phase-overlapped:
//   phase1: xs_hi [4][34][72] bf16 @0 (19584 B), xs_lo @19584 (19584 B)
//   phase2: zbuf  float[64][48] @0 (12288 B),
//           fbuf per wave @12288 + w*9216: fh [64][36] bf16, fl +4608 B
// ---------------------------------------------------------------------------
#define XS_LO_OFF   19584
#define FB_OFF      12288
#define FB_PER_WAVE 9216
#define ARENA_BYTES 49152

__global__ __launch_bounds__(256, 2) void rpn_main(
    const float* __restrict__ x,        // [4][256][256][64]
    const float* __restrict__ b_base,   // [512]
    const float* __restrict__ b_cls,    // [9]
    const float* __restrict__ b_reg,    // [36]
    const __bf16* __restrict__ btI,
    const __bf16* __restrict__ bt2_hi, const __bf16* __restrict__ bt2_lo,
    float* __restrict__ out)            // [4][256][256][45]
{
    __shared__ char smem[ARENA_BYTES];
    __bf16* xs_hi = (__bf16*)smem;
    __bf16* xs_lo = (__bf16*)(smem + XS_LO_OFF);
    float*  zbuf  = (float*)smem;

    const int tid  = threadIdx.x;
    const int wave = tid >> 6;
    const int lane = tid & 63;
    const int q    = lane >> 4;     // 0..3
    const int lr   = lane & 15;     // 0..15
    const int n0   = wave * 128;    // wave's channel-slice base

    const int wg  = blockIdx.x;
    const int b   = wg >> 10;           // 1024 tiles per image
    const int rem = wg & 1023;
    const int h0  = (rem >> 3) * 2;     // 2 h-rows per tile
    const int w0  = (rem & 7) * 32;     // 32 w-positions per tile

    // ---- stage x patch (4 rows x 34 pos x 64 ch) as bf16 hi/lo ----
    for (int i = 0; i < 9; ++i) {
        int flat = tid + i * 256;
        if (flat < 4 * 34 * 16) {
            int cq  = flat & 15;          // channel quad
            int rp  = flat >> 4;          // 0..135
            int row = rp / 34;
            int pos = rp - row * 34;
            int hh  = h0 - 1 + row;
            int ww  = w0 - 1 + pos;
            bf16x4 h4, l4;
            if (hh >= 0 && hh < 256 && ww >= 0 && ww < 256) {
                const float4 v = *(const float4*)&x[(((b * 256 + hh) * 256 + ww) * 64 + cq * 4)];
                float vs[4] = {v.x, v.y, v.z, v.w};
                #pragma unroll
                for (int j = 0; j < 4; ++j) {
                    __bf16 h = (__bf16)vs[j];
                    h4[j] = h;
                    l4[j] = (__bf16)(vs[j] - (float)h);
                }
            } else {
                #pragma unroll
                for (int j = 0; j < 4; ++j) { h4[j] = (__bf16)0.f; l4[j] = (__bf16)0.f; }
            }
            int off = (row * 34 + pos) * 72 + cq * 4;
            *(bf16x4*)&xs_hi[off] = h4;
            *(bf16x4*)&xs_lo[off] = l4;
        }
    }
    __syncthreads();   // barrier 1: xs ready

    // ---- trunk K-loop: 144 si-steps, barrier-free, depth-4 weight prefetch ----
    f32x4 acc[4][8];
    #pragma unroll
    for (int km = 0; km < 4; ++km)
        #pragma unroll
        for (int l = 0; l < 8; ++l)
            acc[km][l] = (f32x4){0.f, 0.f, 0.f, 0.f};

    // per-lane weight stream base: 32 B per si-step (hi8 then lo8)
    const __bf16* bq = btI + (size_t)tid * 16;

    bf16x8 pfh[4], pfl[4];
    #pragma unroll
    for (int p = 0; p < 4; ++p) {
        const __bf16* ptr = bq + (size_t)p * 4096;
        pfh[p] = *(const bf16x8*)ptr;
        pfl[p] = *(const bf16x8*)(ptr + 8);
    }

    for (int s = 0; s < 18; ++s) {
        const int tap = s >> 1;
        const int ky  = tap / 3;
        const int kx  = tap - ky * 3;
        const int c0  = (s & 1) * 32 + q * 8;
        bf16x8 ah[4], al[4];
        #pragma unroll
        for (int km = 0; km < 4; ++km) {
            int rowp = (km >> 1) + ky;
            int pos  = ((km & 1) << 4) + lr + kx;
            int off  = (rowp * 34 + pos) * 72 + c0;
            ah[km] = *(const bf16x8*)&xs_hi[off];
            al[km] = *(const bf16x8*)&xs_lo[off];
        }
        #pragma unroll
        for (int l = 0; l < 8; ++l) {
            const int slot = l & 3;            // (s*8+l) & 3 == l & 3
            bf16x8 bh = pfh[slot], bl = pfl[slot];
            // issue refill for si+4 into the slot just consumed
            {
                int nsi = s * 8 + l + 4;       // <= 147, pad slots allocated
                const __bf16* ptr = bq + (size_t)nsi * 4096;
                pfh[slot] = *(const bf16x8*)ptr;
                pfl[slot] = *(const bf16x8*)(ptr + 8);
            }
            #pragma unroll
            for (int km = 0; km < 4; ++km)
                acc[km][l] = __builtin_amdgcn_mfma_f32_16x16x32_bf16(ah[km], bh, acc[km][l], 0, 0, 0);
            #pragma unroll
            for (int km = 0; km < 4; ++km)
                acc[km][l] = __builtin_amdgcn_mfma_f32_16x16x32_bf16(ah[km], bl, acc[km][l], 0, 0, 0);
            #pragma unroll
            for (int km = 0; km < 4; ++km)
                acc[km][l] = __builtin_amdgcn_mfma_f32_16x16x32_bf16(al[km], bh, acc[km][l], 0, 0, 0);
        }
    }

    __syncthreads();   // barrier 2: xs dead, safe to reuse arena

    // zero the z accumulation buffer
    for (int i = tid; i < 64 * 48; i += 256) zbuf[i] = 0.f;
    __syncthreads();   // barrier 3: zbuf zeroed

    // ---- fused 1x1 heads: per-wave k-slice GEMM feat[64][128] x w2[128][48] ----
    __bf16* fh = (__bf16*)(smem + FB_OFF + wave * FB_PER_WAVE);
    __bf16* fl = fh + 64 * 36;

    f32x4 acc2[4][3];
    #pragma unroll
    for (int km = 0; km < 4; ++km)
        #pragma unroll
        for (int ns = 0; ns < 3; ++ns)
            acc2[km][ns] = (f32x4){0.f, 0.f, 0.f, 0.f};

    for (int sub = 0; sub < 4; ++sub) {       // 4 k-chunks of 32 within the slice
        // dump this wave's 32-channel slice of feat (bias+relu, bf16 hi/lo)
        #pragma unroll
        for (int lh = 0; lh < 2; ++lh) {
            int l = sub * 2 + lh;
            float bias = b_base[n0 + l * 16 + lr];
            #pragma unroll
            for (int km = 0; km < 4; ++km) {
                #pragma unroll
                for (int r = 0; r < 4; ++r) {
                    float v = acc[km][l][r] + bias;
                    v = v > 0.f ? v : 0.f;
                    __bf16 h = (__bf16)v;
                    int row = km * 16 + q * 4 + r;
                    int col = lh * 16 + lr;
                    fh[row * 36 + col] = h;
                    fl[row * 36 + col] = (__bf16)(v - (float)h);
                }
            }
        }
        asm volatile("s_waitcnt lgkmcnt(0)" ::: "memory");  // wave-local RAW fence

        // A-frags: feat rows, k-local = q*8..q*8+7 (8-byte aligned -> 2x b64)
        bf16x8 fah[4], fal[4];
        #pragma unroll
        for (int km = 0; km < 4; ++km) {
            int off = (km * 16 + lr) * 36 + q * 8;
            union { bf16x8 v8; bf16x4 v4[2]; } uh, ul;
            uh.v4[0] = *(const bf16x4*)&fh[off];
            uh.v4[1] = *(const bf16x4*)&fh[off + 4];
            ul.v4[0] = *(const bf16x4*)&fl[off];
            ul.v4[1] = *(const bf16x4*)&fl[off + 4];
            fah[km] = uh.v8;
            fal[km] = ul.v8;
        }

        const int kg = n0 + sub * 32 + q * 8;   // global k for B frags
        // ns = 0 (contains the 9 score cols): 3-pass hi/lo
        {
            int eo = (0 * 16 + lr) * 512 + kg;
            bf16x8 wh = *(const bf16x8*)&bt2_hi[eo];
            bf16x8 wl = *(const bf16x8*)&bt2_lo[eo];
            #pragma unroll
            for (int km = 0; km < 4; ++km)
                acc2[km][0] = __builtin_amdgcn_mfma_f32_16x16x32_bf16(fah[km], wh, acc2[km][0], 0, 0, 0);
            #pragma unroll
            for (int km = 0; km < 4; ++km)
                acc2[km][0] = __builtin_amdgcn_mfma_f32_16x16x32_bf16(fah[km], wl, acc2[km][0], 0, 0, 0);
            #pragma unroll
            for (int km = 0; km < 4; ++km)
                acc2[km][0] = __builtin_amdgcn_mfma_f32_16x16x32_bf16(fal[km], wh, acc2[km][0], 0, 0, 0);
        }
        // ns = 1,2 (pure delta cols): single pass
        #pragma unroll
        for (int ns = 1; ns < 3; ++ns) {
            int eo = (ns * 16 + lr) * 512 + kg;
            bf16x8 wh = *(const bf16x8*)&bt2_hi[eo];
            #pragma unroll
            for (int km = 0; km < 4; ++km)
                acc2[km][ns] = __builtin_amdgcn_mfma_f32_16x16x32_bf16(fah[km], wh, acc2[km][ns], 0, 0, 0);
        }
    }

    // k-slice reduction across waves
    #pragma unroll
    for (int km = 0; km < 4; ++km)
        #pragma unroll
        for (int ns = 0; ns < 3; ++ns)
            #pragma unroll
            for (int r = 0; r < 4; ++r) {
                int row = km * 16 + q * 4 + r;
                int col = ns * 16 + lr;
                atomicAdd(&zbuf[row * 48 + col], acc2[km][ns][r]);
            }
    __syncthreads();   // barrier 4: z complete

    // ---- epilogue: sigmoid, threshold mask, store ----
    for (int i = tid; i < 64 * 45; i += 256) {
        int m = i / 45;
        int o = i - m * 45;
        float z = zbuf[m * 48 + o];
        float v;
        if (o < 9) {
            v = 1.f / (1.f + expf(-(z + b_cls[o])));
        } else {
            int d = o - 9;
            int a = d >> 2;
            float s = 1.f / (1.f + expf(-(zbuf[m * 48 + a] + b_cls[a])));
            v = (s > 0.7f) ? (z + b_reg[d]) : 0.f;
        }
        int mh = m >> 5, mw = m & 31;
        out[(((b * 256 + h0 + mh) * 256) + w0 + mw) * 45 + o] = v;
    }
}

// ---------------------------------------------------------------------------
extern "C" void kernel_launch(void* const* d_in, const int* in_sizes, int n_in,
                              void* d_out, int out_size, void* d_ws, size_t ws_size,
                              hipStream_t stream)
{
    const float* x      = (const float*)d_in[0];
    const float* w_base = (const float*)d_in[1];
    const float* b_base = (const float*)d_in[2];
    const float* w_cls  = (const float*)d_in[3];
    const float* b_cls  = (const float*)d_in[4];
    const float* w_reg  = (const float*)d_in[5];
    const float* b_reg  = (const float*)d_in[6];
    float* out = (float*)d_out;

    __bf16* btI    = (__bf16*)d_ws;
    __bf16* bt2_hi = btI + BTI_ELEMS;
    __bf16* bt2_lo = bt2_hi + BT2_ELEMS;

    rpn_prep<<<(SI_STEPS * 256 * 8 + BT2_ELEMS + 255) / 256, 256, 0, stream>>>(
        w_base, w_cls, w_reg, btI, bt2_hi, bt2_lo);
    rpn_main<<<4096, 256, 0, stream>>>(
        x, b_base, b_cls, b_reg, btI, bt2_hi, bt2_lo, out);
}